// Round 2
// baseline (539.165 us; speedup 1.0000x reference)
//
#include <hip/hip_runtime.h>
#include <cstdint>

using u16 = unsigned short;
typedef short bf16x8 __attribute__((ext_vector_type(8)));
typedef float f32x4 __attribute__((ext_vector_type(4)));

__device__ __forceinline__ float bf2f(u16 h) {
    union { unsigned u; float f; } x;
    x.u = ((unsigned)h) << 16;
    return x.f;
}
__device__ __forceinline__ u16 f2bf(float f) {
    union { float f; unsigned u; } x;
    x.f = f;
    unsigned r = x.u + 0x7fffu + ((x.u >> 16) & 1u);
    return (u16)(r >> 16);
}

// ---------------------------------------------------------------------------
// fp32 -> bf16 elementwise convert (for weights)
// ---------------------------------------------------------------------------
__global__ __launch_bounds__(256) void cvt_f32_bf16(const float* __restrict__ src,
                                                    u16* __restrict__ dst, int n) {
    int i = blockIdx.x * 256 + threadIdx.x;
    if (i < n) dst[i] = f2bf(src[i]);
}

// ---------------------------------------------------------------------------
// [B][C][N] fp32 -> [B][N][dst_stride] bf16 transpose (col offset col_off)
// ---------------------------------------------------------------------------
__global__ __launch_bounds__(256) void transpose_to_bf16(const float* __restrict__ src,
                                                         u16* __restrict__ dst,
                                                         int C, int N, int dst_stride,
                                                         int col_off) {
    __shared__ float tile[32][33];
    int b = blockIdx.z;
    int n0 = blockIdx.x * 32, c0 = blockIdx.y * 32;
    int tx = threadIdx.x & 31, ty = threadIdx.x >> 5;  // 32 x 8
    const float* s = src + (long)b * C * N;
#pragma unroll
    for (int i = 0; i < 4; i++) {
        int c = ty + i * 8;
        tile[c][tx] = s[(long)(c0 + c) * N + n0 + tx];
    }
    __syncthreads();
    u16* d = dst + (long)b * N * dst_stride;
#pragma unroll
    for (int i = 0; i < 4; i++) {
        int n = ty + i * 8;
        // R1 FIX: column index must include the channel-block offset c0
        // (was col_off + tx — all gridDim.y blocks overwrote columns [0,32)).
        d[(long)(n0 + n) * dst_stride + col_off + c0 + tx] = f2bf(tile[tx][n]);
    }
}

// ---------------------------------------------------------------------------
// kNN(3) + inverse-distance interpolation.
// Block = 256 threads = 256 query points; grid = (N1/256, B).
// Writes interpolated features (bf16) into X[s][128..383].
// ---------------------------------------------------------------------------
#define N1 8192
#define N2 2048
#define C2 256

__global__ __launch_bounds__(256) void knn_interp(const float* __restrict__ xyz1,
                                                  const float* __restrict__ xyz2,
                                                  const u16* __restrict__ P2T,  // [B][N2][C2]
                                                  u16* __restrict__ X) {       // [B*N1][384]
    __shared__ float4 pts[N2];
    __shared__ int s_idx[256][3];
    __shared__ float s_w[256][3];
    int b = blockIdx.y;
    int n0 = blockIdx.x * 256;
    int tid = threadIdx.x;

    // stage xyz2[b] into LDS with squared norm (ref formula: ((x*x+y*y)+z*z), no FMA)
    for (int j = tid; j < N2; j += 256) {
        float x = xyz2[((long)b * N2 + j) * 3 + 0];
        float y = xyz2[((long)b * N2 + j) * 3 + 1];
        float z = xyz2[((long)b * N2 + j) * 3 + 2];
        float nsq = __fadd_rn(__fadd_rn(__fmul_rn(x, x), __fmul_rn(y, y)), __fmul_rn(z, z));
        pts[j] = make_float4(x, y, z, nsq);
    }
    __syncthreads();

    int n = n0 + tid;
    float px = xyz1[((long)b * N1 + n) * 3 + 0];
    float py = xyz1[((long)b * N1 + n) * 3 + 1];
    float pz = xyz1[((long)b * N1 + n) * 3 + 2];
    float psq = __fadd_rn(__fadd_rn(__fmul_rn(px, px), __fmul_rn(py, py)), __fmul_rn(pz, pz));

    float d0 = 1e30f, d1 = 1e30f, d2 = 1e30f;
    int i0 = 0, i1 = 0, i2 = 0;
#pragma unroll 4
    for (int j = 0; j < N2; j++) {
        float4 p = pts[j];
        // replicate np: sq = (|p1|^2 + |p2|^2) - 2*dot, non-contracted fp32
        float dot = __fadd_rn(__fadd_rn(__fmul_rn(px, p.x), __fmul_rn(py, p.y)),
                              __fmul_rn(pz, p.z));
        float sq = __fsub_rn(__fadd_rn(psq, p.w), __fmul_rn(2.0f, dot));
        float d = sqrtf(fmaxf(sq, 0.0f));
        if (d < d2) {
            if (d < d1) {
                d2 = d1; i2 = i1;
                if (d < d0) { d1 = d0; i1 = i0; d0 = d; i0 = j; }
                else        { d1 = d;  i1 = j; }
            } else { d2 = d; i2 = j; }
        }
    }
    float kd0 = fmaxf(d0, 1e-10f), kd1 = fmaxf(d1, 1e-10f), kd2 = fmaxf(d2, 1e-10f);
    float w0 = __fdiv_rn(1.0f, kd0), w1 = __fdiv_rn(1.0f, kd1), w2 = __fdiv_rn(1.0f, kd2);
    float wsum = __fadd_rn(__fadd_rn(w0, w1), w2);
    s_idx[tid][0] = i0; s_idx[tid][1] = i1; s_idx[tid][2] = i2;
    s_w[tid][0] = __fdiv_rn(w0, wsum);
    s_w[tid][1] = __fdiv_rn(w1, wsum);
    s_w[tid][2] = __fdiv_rn(w2, wsum);
    __syncthreads();

    // cooperative gather: per point p, 256 threads cover the 256 channels (coalesced)
    int c = tid;
    const u16* base = P2T + (long)b * N2 * C2;
    for (int p = 0; p < 256; p++) {
        int j0 = s_idx[p][0], j1 = s_idx[p][1], j2 = s_idx[p][2];
        float f0 = bf2f(base[(long)j0 * C2 + c]);
        float f1 = bf2f(base[(long)j1 * C2 + c]);
        float f2 = bf2f(base[(long)j2 * C2 + c]);
        float acc = __fadd_rn(__fadd_rn(__fmul_rn(f0, s_w[p][0]), __fmul_rn(f1, s_w[p][1])),
                              __fmul_rn(f2, s_w[p][2]));
        X[(long)(b * N1 + n0 + p) * 384 + 128 + c] = f2bf(acc);
    }
}

// ---------------------------------------------------------------------------
// bf16 MFMA GEMM: Y[M][Ntot] = A[M][KDIM] * Bw[Ntot][KDIM]^T + bias
// Block tile 128x128, 4 waves each 64x64 (4x4 of 16x16x32 MFMA).
// Optional fused BN+ReLU on the input (per-k scale/shift from global stats).
// Epilogue accumulates per-output-channel sum / sumsq via atomics.
// ---------------------------------------------------------------------------
template <int KDIM, bool BN_IN, bool OUT_BF16>
__global__ __launch_bounds__(256) void gemm_bn(const u16* __restrict__ A,
                                               const u16* __restrict__ Bw,
                                               const float* __restrict__ bias,
                                               const float* __restrict__ g_in_sum,
                                               const float* __restrict__ g_in_ssq,
                                               const float* __restrict__ gamma_in,
                                               const float* __restrict__ beta_in,
                                               void* __restrict__ Yout, int Ntot,
                                               float* __restrict__ g_out_sum,
                                               float* __restrict__ g_out_ssq) {
    __shared__ __align__(16) u16 Al[128 * 40];  // +8 pad: conflict-free ds_read_b128
    __shared__ __align__(16) u16 Bl[128 * 40];
    __shared__ float s_stats[256];
    __shared__ float s_scale[BN_IN ? KDIM : 2];
    __shared__ float s_shift[BN_IN ? KDIM : 2];

    int tid = threadIdx.x;
    long s0 = (long)blockIdx.x * 128;
    int o0 = blockIdx.y * 128;

    s_stats[tid < 256 ? tid : 0] = 0.0f;
    if constexpr (BN_IN) {
        for (int k = tid; k < KDIM; k += 256) {
            float mu = g_in_sum[k] * (1.0f / 65536.0f);
            float var = g_in_ssq[k] * (1.0f / 65536.0f) - mu * mu;
            float rs = rsqrtf(var + 1e-5f);
            float sc = gamma_in[k] * rs;
            s_scale[k] = sc;
            s_shift[k] = beta_in[k] - mu * sc;
        }
    }
    int wid = tid >> 6, lane = tid & 63;
    int wm = wid >> 1, wn = wid & 1;
    int q = lane >> 4, l16 = lane & 15;

    f32x4 acc[4][4];
#pragma unroll
    for (int mi = 0; mi < 4; mi++)
#pragma unroll
        for (int ni = 0; ni < 4; ni++) acc[mi][ni] = (f32x4){0.f, 0.f, 0.f, 0.f};
    __syncthreads();

    for (int kt = 0; kt < KDIM; kt += 32) {
#pragma unroll
        for (int cc = 0; cc < 2; cc++) {
            int ci = tid + cc * 256;
            int row = ci >> 2;
            int kc = (ci & 3) << 3;
            union { uint4 u; u16 h[8]; } va;
            va.u = *(const uint4*)(A + (s0 + row) * KDIM + kt + kc);
            if constexpr (BN_IN) {
#pragma unroll
                for (int j = 0; j < 8; j++) {
                    float f = bf2f(va.h[j]);
                    f = fmaxf(fmaf(f, s_scale[kt + kc + j], s_shift[kt + kc + j]), 0.0f);
                    va.h[j] = f2bf(f);
                }
            }
            *(uint4*)&Al[row * 40 + kc] = va.u;
            *(uint4*)&Bl[row * 40 + kc] = *(const uint4*)(Bw + (long)(o0 + row) * KDIM + kt + kc);
        }
        __syncthreads();
        bf16x8 af[4], bfr[4];
#pragma unroll
        for (int mi = 0; mi < 4; mi++)
            af[mi] = *(const bf16x8*)&Al[(wm * 64 + mi * 16 + l16) * 40 + q * 8];
#pragma unroll
        for (int ni = 0; ni < 4; ni++)
            bfr[ni] = *(const bf16x8*)&Bl[(wn * 64 + ni * 16 + l16) * 40 + q * 8];
#pragma unroll
        for (int mi = 0; mi < 4; mi++)
#pragma unroll
            for (int ni = 0; ni < 4; ni++)
                acc[mi][ni] = __builtin_amdgcn_mfma_f32_16x16x32_bf16(af[mi], bfr[ni],
                                                                      acc[mi][ni], 0, 0, 0);
        __syncthreads();
    }

    // epilogue: bias add, store, per-channel sum/sumsq
#pragma unroll
    for (int ni = 0; ni < 4; ni++) {
        int coll = wn * 64 + ni * 16 + l16;
        int col = o0 + coll;
        float bz = bias[col];
        float s1 = 0.0f, s2 = 0.0f;
#pragma unroll
        for (int mi = 0; mi < 4; mi++) {
#pragma unroll
            for (int r = 0; r < 4; r++) {
                float v = acc[mi][ni][r] + bz;
                s1 += v;
                s2 += v * v;
                long row = s0 + wm * 64 + mi * 16 + q * 4 + r;
                if constexpr (OUT_BF16)
                    ((u16*)Yout)[row * Ntot + col] = f2bf(v);
                else
                    ((float*)Yout)[row * Ntot + col] = v;
            }
        }
        s1 += __shfl_xor(s1, 16, 64);
        s1 += __shfl_xor(s1, 32, 64);
        s2 += __shfl_xor(s2, 16, 64);
        s2 += __shfl_xor(s2, 32, 64);
        if (q == 0) {
            atomicAdd(&s_stats[coll], s1);
            atomicAdd(&s_stats[128 + coll], s2);
        }
    }
    __syncthreads();
    if (tid < 128) {
        atomicAdd(&g_out_sum[o0 + tid], s_stats[tid]);
        atomicAdd(&g_out_ssq[o0 + tid], s_stats[128 + tid]);
    }
}

// ---------------------------------------------------------------------------
// final BN+ReLU + transpose to [B][128][N1] fp32
// ---------------------------------------------------------------------------
__global__ __launch_bounds__(256) void finalize_k(const float* __restrict__ Y1,  // [M][128]
                                                  const float* __restrict__ g_sum,
                                                  const float* __restrict__ g_ssq,
                                                  const float* __restrict__ gamma,
                                                  const float* __restrict__ beta,
                                                  float* __restrict__ out) {
    __shared__ float s_scale[128], s_shift[128];
    int tid = threadIdx.x;
    if (tid < 128) {
        float mu = g_sum[tid] * (1.0f / 65536.0f);
        float var = g_ssq[tid] * (1.0f / 65536.0f) - mu * mu;
        float rs = rsqrtf(var + 1e-5f);
        float sc = gamma[tid] * rs;
        s_scale[tid] = sc;
        s_shift[tid] = beta[tid] - mu * sc;
    }
    __syncthreads();
    long s = (long)blockIdx.x * 256 + tid;
    int b = (int)(s >> 13);
    int n = (int)(s & 8191);
    const float* yrow = Y1 + s * 128;
    float* obase = out + (long)b * 128 * 8192 + n;
#pragma unroll 8
    for (int o = 0; o < 128; o++) {
        float v = fmaxf(fmaf(yrow[o], s_scale[o], s_shift[o]), 0.0f);
        obase[(long)o * 8192] = v;
    }
}

// ---------------------------------------------------------------------------
// launch
// ---------------------------------------------------------------------------
extern "C" void kernel_launch(void* const* d_in, const int* in_sizes, int n_in,
                              void* d_out, int out_size, void* d_ws, size_t ws_size,
                              hipStream_t stream) {
    const float* xyz1   = (const float*)d_in[0];
    const float* xyz2   = (const float*)d_in[1];
    const float* points1 = (const float*)d_in[2];
    const float* points2 = (const float*)d_in[3];
    const float* w0 = (const float*)d_in[4];
    const float* b0 = (const float*)d_in[5];
    const float* gamma0 = (const float*)d_in[6];
    const float* beta0 = (const float*)d_in[7];
    const float* w1 = (const float*)d_in[8];
    const float* b1 = (const float*)d_in[9];
    const float* gamma1 = (const float*)d_in[10];
    const float* beta1 = (const float*)d_in[11];
    float* out = (float*)d_out;

    char* ws = (char*)d_ws;
    // ws layout (all 256B aligned)
    u16* X    = (u16*)(ws + 0);            // 65536 x 384 bf16 = 50,331,648
    u16* P2T  = (u16*)(ws + 50331648);     // 8 x 2048 x 256 bf16 = 8,388,608
    u16* w0b  = (u16*)(ws + 58720256);     // 256 x 384 bf16 = 196,608
    u16* w1b  = (u16*)(ws + 58916864);     // 128 x 256 bf16 = 65,536
    u16* Y0   = (u16*)(ws + 58982400);     // 65536 x 256 bf16 = 33,554,432
    float* Y1 = (float*)(ws + 92536832);   // 65536 x 128 f32 = 33,554,432
    float* stats = (float*)(ws + 126091264);  // 768 floats
    if (ws_size < 126094336) return;  // insufficient scratch -> visible failure
    float* gsum0 = stats;
    float* gss0  = stats + 256;
    float* gsum1 = stats + 512;
    float* gss1  = stats + 640;

    hipMemsetAsync(stats, 0, 768 * sizeof(float), stream);
    cvt_f32_bf16<<<384, 256, 0, stream>>>(w0, w0b, 98304);
    cvt_f32_bf16<<<128, 256, 0, stream>>>(w1, w1b, 32768);
    transpose_to_bf16<<<dim3(256, 4, 8), 256, 0, stream>>>(points1, X, 128, 8192, 384, 0);
    transpose_to_bf16<<<dim3(64, 8, 8), 256, 0, stream>>>(points2, P2T, 256, 2048, 256, 0);
    knn_interp<<<dim3(32, 8), 256, 0, stream>>>(xyz1, xyz2, P2T, X);
    gemm_bn<384, false, true><<<dim3(512, 2), 256, 0, stream>>>(
        X, w0b, b0, nullptr, nullptr, nullptr, nullptr, Y0, 256, gsum0, gss0);
    gemm_bn<256, true, false><<<dim3(512, 1), 256, 0, stream>>>(
        Y0, w1b, b1, gsum0, gss0, gamma0, beta0, Y1, 128, gsum1, gss1);
    finalize_k<<<256, 256, 0, stream>>>(Y1, gsum1, gss1, gamma1, beta1, out);
}

// Round 3
// 281.939 us; speedup vs baseline: 1.9123x; 1.9123x over previous
//
#include <hip/hip_runtime.h>
#include <cstdint>

using u16 = unsigned short;
typedef short bf16x8 __attribute__((ext_vector_type(8)));
typedef float f32x4 __attribute__((ext_vector_type(4)));

__device__ __forceinline__ float bf2f(u16 h) {
    union { unsigned u; float f; } x;
    x.u = ((unsigned)h) << 16;
    return x.f;
}
__device__ __forceinline__ u16 f2bf(float f) {
    union { float f; unsigned u; } x;
    x.f = f;
    unsigned r = x.u + 0x7fffu + ((x.u >> 16) & 1u);
    return (u16)(r >> 16);
}

// ---------------------------------------------------------------------------
// fp32 -> bf16 elementwise convert (for weights)
// ---------------------------------------------------------------------------
__global__ __launch_bounds__(256) void cvt_f32_bf16(const float* __restrict__ src,
                                                    u16* __restrict__ dst, int n) {
    int i = blockIdx.x * 256 + threadIdx.x;
    if (i < n) dst[i] = f2bf(src[i]);
}

// ---------------------------------------------------------------------------
// [B][C][N] fp32 -> [B][N][dst_stride] bf16 transpose (col offset col_off)
// ---------------------------------------------------------------------------
__global__ __launch_bounds__(256) void transpose_to_bf16(const float* __restrict__ src,
                                                         u16* __restrict__ dst,
                                                         int C, int N, int dst_stride,
                                                         int col_off) {
    __shared__ float tile[32][33];
    int b = blockIdx.z;
    int n0 = blockIdx.x * 32, c0 = blockIdx.y * 32;
    int tx = threadIdx.x & 31, ty = threadIdx.x >> 5;  // 32 x 8
    const float* s = src + (long)b * C * N;
#pragma unroll
    for (int i = 0; i < 4; i++) {
        int c = ty + i * 8;
        tile[c][tx] = s[(long)(c0 + c) * N + n0 + tx];
    }
    __syncthreads();
    u16* d = dst + (long)b * N * dst_stride;
#pragma unroll
    for (int i = 0; i < 4; i++) {
        int n = ty + i * 8;
        d[(long)(n0 + n) * dst_stride + col_off + c0 + tx] = f2bf(tile[tx][n]);
    }
}

// ---------------------------------------------------------------------------
// kNN(3) + inverse-distance interpolation, v2 (R2).
// R1 version: 256 blocks = 1 block/CU -> Occupancy 11.7%, latency-bound.
// v2: block = 64 queries x 4 scanner threads (each scans 512 of 2048
// candidates by SQUARED distance), 12-way (sq,idx) lexicographic merge in
// LDS, sqrt only for the 3 winners. Grid 128x8 = 1024 blocks = 4/CU
// (LDS ~40KB caps at 4). Gather phase vectorized to ushort4.
// ---------------------------------------------------------------------------
#define N1 8192
#define N2 2048
#define C2 256

__global__ __launch_bounds__(256) void knn_interp(const float* __restrict__ xyz1,
                                                  const float* __restrict__ xyz2,
                                                  const u16* __restrict__ P2T,  // [B][N2][C2]
                                                  u16* __restrict__ X) {       // [B*N1][384]
    __shared__ float4 pts[N2];          // 32768 B
    __shared__ float m_d[4][64][3];     // 3072 B partial top-3 (squared dist)
    __shared__ int   m_i[4][64][3];     // 3072 B
    __shared__ int   s_idx[64][3];
    __shared__ float s_w[64][3];
    int b = blockIdx.y;
    int n0 = blockIdx.x * 64;
    int tid = threadIdx.x;
    int ql = tid & 63;       // query within block
    int part = tid >> 6;     // candidate partition 0..3 (== wave id)

    // stage xyz2[b] into LDS with squared norm (ref formula: ((x*x+y*y)+z*z), no FMA)
    for (int j = tid; j < N2; j += 256) {
        float x = xyz2[((long)b * N2 + j) * 3 + 0];
        float y = xyz2[((long)b * N2 + j) * 3 + 1];
        float z = xyz2[((long)b * N2 + j) * 3 + 2];
        float nsq = __fadd_rn(__fadd_rn(__fmul_rn(x, x), __fmul_rn(y, y)), __fmul_rn(z, z));
        pts[j] = make_float4(x, y, z, nsq);
    }
    __syncthreads();

    int n = n0 + ql;
    float px = xyz1[((long)b * N1 + n) * 3 + 0];
    float py = xyz1[((long)b * N1 + n) * 3 + 1];
    float pz = xyz1[((long)b * N1 + n) * 3 + 2];
    float psq = __fadd_rn(__fadd_rn(__fmul_rn(px, px), __fmul_rn(py, py)), __fmul_rn(pz, pz));

    // scan 512 candidates by squared distance (sqrt is monotonic; exact d for
    // the winners is computed after the merge). Within-part ascending j +
    // strict < preserves lower-index-wins ties.
    float b0 = 1e30f, b1 = 1e30f, b2 = 1e30f;
    int i0 = 0, i1 = 0, i2 = 0;
    int jbeg = part * (N2 / 4);
#pragma unroll 8
    for (int jj = 0; jj < N2 / 4; jj++) {
        int j = jbeg + jj;
        float4 p = pts[j];  // j uniform across the wave -> LDS broadcast
        float dot = __fadd_rn(__fadd_rn(__fmul_rn(px, p.x), __fmul_rn(py, p.y)),
                              __fmul_rn(pz, p.z));
        float sq = __fsub_rn(__fadd_rn(psq, p.w), __fmul_rn(2.0f, dot));
        if (sq < b2) {
            if (sq < b1) {
                b2 = b1; i2 = i1;
                if (sq < b0) { b1 = b0; i1 = i0; b0 = sq; i0 = j; }
                else         { b1 = sq; i1 = j; }
            } else { b2 = sq; i2 = j; }
        }
    }
    m_d[part][ql][0] = b0; m_d[part][ql][1] = b1; m_d[part][ql][2] = b2;
    m_i[part][ql][0] = i0; m_i[part][ql][1] = i1; m_i[part][ql][2] = i2;
    __syncthreads();

    // merge 4x3 partials -> top-3, lexicographic (sq, idx). Parts scan
    // disjoint ascending ranges so all 12 entries are distinct candidates.
    if (tid < 64) {
        float c0 = 1e30f, c1 = 1e30f, c2 = 1e30f;
        int a0 = 0x7fffffff, a1 = 0x7fffffff, a2 = 0x7fffffff;
#pragma unroll
        for (int pp = 0; pp < 4; pp++) {
#pragma unroll
            for (int k = 0; k < 3; k++) {
                float d = m_d[pp][tid][k];
                int ix = m_i[pp][tid][k];
                if (d < c2 || (d == c2 && ix < a2)) {
                    if (d < c1 || (d == c1 && ix < a1)) {
                        c2 = c1; a2 = a1;
                        if (d < c0 || (d == c0 && ix < a0)) { c1 = c0; a1 = a0; c0 = d; a0 = ix; }
                        else                                { c1 = d; a1 = ix; }
                    } else { c2 = d; a2 = ix; }
                }
            }
        }
        // exact reference math for the winners: d = sqrt(max(sq,0)), clamp 1e-10
        float e0 = sqrtf(fmaxf(c0, 0.0f));
        float e1 = sqrtf(fmaxf(c1, 0.0f));
        float e2 = sqrtf(fmaxf(c2, 0.0f));
        float kd0 = fmaxf(e0, 1e-10f), kd1 = fmaxf(e1, 1e-10f), kd2 = fmaxf(e2, 1e-10f);
        float w0 = __fdiv_rn(1.0f, kd0), w1 = __fdiv_rn(1.0f, kd1), w2 = __fdiv_rn(1.0f, kd2);
        float wsum = __fadd_rn(__fadd_rn(w0, w1), w2);
        s_idx[tid][0] = a0; s_idx[tid][1] = a1; s_idx[tid][2] = a2;
        s_w[tid][0] = __fdiv_rn(w0, wsum);
        s_w[tid][1] = __fdiv_rn(w1, wsum);
        s_w[tid][2] = __fdiv_rn(w2, wsum);
    }
    __syncthreads();

    // gather: wave w handles queries p = w, w+4, ...; lane l covers channels
    // [4l, 4l+4) as ushort4 (8 B/lane, coalesced 512 B/wave).
    int l = tid & 63;
    const u16* base = P2T + (long)b * N2 * C2;
    for (int p = part; p < 64; p += 4) {
        int j0 = s_idx[p][0], j1 = s_idx[p][1], j2 = s_idx[p][2];  // broadcast
        float f0 = s_w[p][0], f1 = s_w[p][1], f2 = s_w[p][2];
        ushort4 r0 = *(const ushort4*)&base[(long)j0 * C2 + l * 4];
        ushort4 r1 = *(const ushort4*)&base[(long)j1 * C2 + l * 4];
        ushort4 r2 = *(const ushort4*)&base[(long)j2 * C2 + l * 4];
        ushort4 o;
        {
            float acc = __fadd_rn(__fadd_rn(__fmul_rn(bf2f(r0.x), f0), __fmul_rn(bf2f(r1.x), f1)),
                                  __fmul_rn(bf2f(r2.x), f2));
            o.x = f2bf(acc);
        }
        {
            float acc = __fadd_rn(__fadd_rn(__fmul_rn(bf2f(r0.y), f0), __fmul_rn(bf2f(r1.y), f1)),
                                  __fmul_rn(bf2f(r2.y), f2));
            o.y = f2bf(acc);
        }
        {
            float acc = __fadd_rn(__fadd_rn(__fmul_rn(bf2f(r0.z), f0), __fmul_rn(bf2f(r1.z), f1)),
                                  __fmul_rn(bf2f(r2.z), f2));
            o.z = f2bf(acc);
        }
        {
            float acc = __fadd_rn(__fadd_rn(__fmul_rn(bf2f(r0.w), f0), __fmul_rn(bf2f(r1.w), f1)),
                                  __fmul_rn(bf2f(r2.w), f2));
            o.w = f2bf(acc);
        }
        *(ushort4*)&X[(long)(b * N1 + n0 + p) * 384 + 128 + l * 4] = o;
    }
}

// ---------------------------------------------------------------------------
// bf16 MFMA GEMM: Y[M][Ntot] = A[M][KDIM] * Bw[Ntot][KDIM]^T + bias
// Block tile 128x128, 4 waves each 64x64 (4x4 of 16x16x32 MFMA).
// Optional fused BN+ReLU on the input (per-k scale/shift from global stats).
// Epilogue accumulates per-output-channel sum / sumsq via atomics.
// ---------------------------------------------------------------------------
template <int KDIM, bool BN_IN, bool OUT_BF16>
__global__ __launch_bounds__(256) void gemm_bn(const u16* __restrict__ A,
                                               const u16* __restrict__ Bw,
                                               const float* __restrict__ bias,
                                               const float* __restrict__ g_in_sum,
                                               const float* __restrict__ g_in_ssq,
                                               const float* __restrict__ gamma_in,
                                               const float* __restrict__ beta_in,
                                               void* __restrict__ Yout, int Ntot,
                                               float* __restrict__ g_out_sum,
                                               float* __restrict__ g_out_ssq) {
    __shared__ __align__(16) u16 Al[128 * 40];  // +8 pad: conflict-free ds_read_b128
    __shared__ __align__(16) u16 Bl[128 * 40];
    __shared__ float s_stats[256];
    __shared__ float s_scale[BN_IN ? KDIM : 2];
    __shared__ float s_shift[BN_IN ? KDIM : 2];

    int tid = threadIdx.x;
    long s0 = (long)blockIdx.x * 128;
    int o0 = blockIdx.y * 128;

    s_stats[tid < 256 ? tid : 0] = 0.0f;
    if constexpr (BN_IN) {
        for (int k = tid; k < KDIM; k += 256) {
            float mu = g_in_sum[k] * (1.0f / 65536.0f);
            float var = g_in_ssq[k] * (1.0f / 65536.0f) - mu * mu;
            float rs = rsqrtf(var + 1e-5f);
            float sc = gamma_in[k] * rs;
            s_scale[k] = sc;
            s_shift[k] = beta_in[k] - mu * sc;
        }
    }
    int wid = tid >> 6, lane = tid & 63;
    int wm = wid >> 1, wn = wid & 1;
    int q = lane >> 4, l16 = lane & 15;

    f32x4 acc[4][4];
#pragma unroll
    for (int mi = 0; mi < 4; mi++)
#pragma unroll
        for (int ni = 0; ni < 4; ni++) acc[mi][ni] = (f32x4){0.f, 0.f, 0.f, 0.f};
    __syncthreads();

    for (int kt = 0; kt < KDIM; kt += 32) {
#pragma unroll
        for (int cc = 0; cc < 2; cc++) {
            int ci = tid + cc * 256;
            int row = ci >> 2;
            int kc = (ci & 3) << 3;
            union { uint4 u; u16 h[8]; } va;
            va.u = *(const uint4*)(A + (s0 + row) * KDIM + kt + kc);
            if constexpr (BN_IN) {
#pragma unroll
                for (int j = 0; j < 8; j++) {
                    float f = bf2f(va.h[j]);
                    f = fmaxf(fmaf(f, s_scale[kt + kc + j], s_shift[kt + kc + j]), 0.0f);
                    va.h[j] = f2bf(f);
                }
            }
            *(uint4*)&Al[row * 40 + kc] = va.u;
            *(uint4*)&Bl[row * 40 + kc] = *(const uint4*)(Bw + (long)(o0 + row) * KDIM + kt + kc);
        }
        __syncthreads();
        bf16x8 af[4], bfr[4];
#pragma unroll
        for (int mi = 0; mi < 4; mi++)
            af[mi] = *(const bf16x8*)&Al[(wm * 64 + mi * 16 + l16) * 40 + q * 8];
#pragma unroll
        for (int ni = 0; ni < 4; ni++)
            bfr[ni] = *(const bf16x8*)&Bl[(wn * 64 + ni * 16 + l16) * 40 + q * 8];
#pragma unroll
        for (int mi = 0; mi < 4; mi++)
#pragma unroll
            for (int ni = 0; ni < 4; ni++)
                acc[mi][ni] = __builtin_amdgcn_mfma_f32_16x16x32_bf16(af[mi], bfr[ni],
                                                                      acc[mi][ni], 0, 0, 0);
        __syncthreads();
    }

    // epilogue: bias add, store, per-channel sum/sumsq
#pragma unroll
    for (int ni = 0; ni < 4; ni++) {
        int coll = wn * 64 + ni * 16 + l16;
        int col = o0 + coll;
        float bz = bias[col];
        float s1 = 0.0f, s2 = 0.0f;
#pragma unroll
        for (int mi = 0; mi < 4; mi++) {
#pragma unroll
            for (int r = 0; r < 4; r++) {
                float v = acc[mi][ni][r] + bz;
                s1 += v;
                s2 += v * v;
                long row = s0 + wm * 64 + mi * 16 + q * 4 + r;
                if constexpr (OUT_BF16)
                    ((u16*)Yout)[row * Ntot + col] = f2bf(v);
                else
                    ((float*)Yout)[row * Ntot + col] = v;
            }
        }
        s1 += __shfl_xor(s1, 16, 64);
        s1 += __shfl_xor(s1, 32, 64);
        s2 += __shfl_xor(s2, 16, 64);
        s2 += __shfl_xor(s2, 32, 64);
        if (q == 0) {
            atomicAdd(&s_stats[coll], s1);
            atomicAdd(&s_stats[128 + coll], s2);
        }
    }
    __syncthreads();
    if (tid < 128) {
        atomicAdd(&g_out_sum[o0 + tid], s_stats[tid]);
        atomicAdd(&g_out_ssq[o0 + tid], s_stats[128 + tid]);
    }
}

// ---------------------------------------------------------------------------
// final BN+ReLU + transpose to [B][128][N1] fp32
// ---------------------------------------------------------------------------
__global__ __launch_bounds__(256) void finalize_k(const float* __restrict__ Y1,  // [M][128]
                                                  const float* __restrict__ g_sum,
                                                  const float* __restrict__ g_ssq,
                                                  const float* __restrict__ gamma,
                                                  const float* __restrict__ beta,
                                                  float* __restrict__ out) {
    __shared__ float s_scale[128], s_shift[128];
    int tid = threadIdx.x;
    if (tid < 128) {
        float mu = g_sum[tid] * (1.0f / 65536.0f);
        float var = g_ssq[tid] * (1.0f / 65536.0f) - mu * mu;
        float rs = rsqrtf(var + 1e-5f);
        float sc = gamma[tid] * rs;
        s_scale[tid] = sc;
        s_shift[tid] = beta[tid] - mu * sc;
    }
    __syncthreads();
    long s = (long)blockIdx.x * 256 + tid;
    int b = (int)(s >> 13);
    int n = (int)(s & 8191);
    const float* yrow = Y1 + s * 128;
    float* obase = out + (long)b * 128 * 8192 + n;
#pragma unroll 8
    for (int o = 0; o < 128; o++) {
        float v = fmaxf(fmaf(yrow[o], s_scale[o], s_shift[o]), 0.0f);
        obase[(long)o * 8192] = v;
    }
}

// ---------------------------------------------------------------------------
// launch
// ---------------------------------------------------------------------------
extern "C" void kernel_launch(void* const* d_in, const int* in_sizes, int n_in,
                              void* d_out, int out_size, void* d_ws, size_t ws_size,
                              hipStream_t stream) {
    const float* xyz1   = (const float*)d_in[0];
    const float* xyz2   = (const float*)d_in[1];
    const float* points1 = (const float*)d_in[2];
    const float* points2 = (const float*)d_in[3];
    const float* w0 = (const float*)d_in[4];
    const float* b0 = (const float*)d_in[5];
    const float* gamma0 = (const float*)d_in[6];
    const float* beta0 = (const float*)d_in[7];
    const float* w1 = (const float*)d_in[8];
    const float* b1 = (const float*)d_in[9];
    const float* gamma1 = (const float*)d_in[10];
    const float* beta1 = (const float*)d_in[11];
    float* out = (float*)d_out;

    char* ws = (char*)d_ws;
    // ws layout (all 256B aligned)
    u16* X    = (u16*)(ws + 0);            // 65536 x 384 bf16 = 50,331,648
    u16* P2T  = (u16*)(ws + 50331648);     // 8 x 2048 x 256 bf16 = 8,388,608
    u16* w0b  = (u16*)(ws + 58720256);     // 256 x 384 bf16 = 196,608
    u16* w1b  = (u16*)(ws + 58916864);     // 128 x 256 bf16 = 65,536
    u16* Y0   = (u16*)(ws + 58982400);     // 65536 x 256 bf16 = 33,554,432
    float* Y1 = (float*)(ws + 92536832);   // 65536 x 128 f32 = 33,554,432
    float* stats = (float*)(ws + 126091264);  // 768 floats
    if (ws_size < 126094336) return;  // insufficient scratch -> visible failure
    float* gsum0 = stats;
    float* gss0  = stats + 256;
    float* gsum1 = stats + 512;
    float* gss1  = stats + 640;

    hipMemsetAsync(stats, 0, 768 * sizeof(float), stream);
    cvt_f32_bf16<<<384, 256, 0, stream>>>(w0, w0b, 98304);
    cvt_f32_bf16<<<128, 256, 0, stream>>>(w1, w1b, 32768);
    transpose_to_bf16<<<dim3(256, 4, 8), 256, 0, stream>>>(points1, X, 128, 8192, 384, 0);
    transpose_to_bf16<<<dim3(64, 8, 8), 256, 0, stream>>>(points2, P2T, 256, 2048, 256, 0);
    knn_interp<<<dim3(128, 8), 256, 0, stream>>>(xyz1, xyz2, P2T, X);
    gemm_bn<384, false, true><<<dim3(512, 2), 256, 0, stream>>>(
        X, w0b, b0, nullptr, nullptr, nullptr, nullptr, Y0, 256, gsum0, gss0);
    gemm_bn<256, true, false><<<dim3(512, 1), 256, 0, stream>>>(
        Y0, w1b, b1, gsum0, gss0, gamma0, beta0, Y1, 128, gsum1, gss1);
    finalize_k<<<256, 256, 0, stream>>>(Y1, gsum1, gss1, gamma1, beta1, out);
}